// Round 8
// baseline (121.486 us; speedup 1.0000x reference)
//
#include <hip/hip_runtime.h>
#include <math.h>

#define KM 192
#define KG 48            // KM/4 object groups (4 objects packed in 3 float4)
#define EPSF 1e-6f
#define QMIN 0.5f
#define BLK 256

__device__ __forceinline__ float clipb(float b) {
    return fminf(fmaxf(b, 1e-4f), 1.0f - 1e-4f);
}
// atanh(b) = 0.5*ln((1+b)/(1-b)); b in [1e-4, 1-1e-4]
__device__ __forceinline__ float fast_atanh(float b) {
    float r = (1.f + b) * __builtin_amdgcn_rcpf(1.f - b);
    return 0.34657359f * __builtin_amdgcn_logf(r);
}

// ---- K1: per-block LDS argmax -> global atomicMax; last block builds packed alpha ----
// pack = (bits(clip(beta)) << 32) | (N-1-i): beta>0 -> bits monotone; low word
// reproduces jnp.argmax first-index tiebreak. argmax(beta) == argmax(q).
// Packed alpha layout pk[e][g] = {(x0,y0,x1,y1),(x2,y2,x3,y3),(q0,q1,q2,q3)}.
__global__ void __launch_bounds__(BLK)
k_amax(const float* __restrict__ beta, const int* __restrict__ tidx,
       const float* __restrict__ cc,
       unsigned long long* __restrict__ packs,
       float* __restrict__ pkf, float* __restrict__ abw,
       unsigned int* __restrict__ cnt, int N, int B) {
    const int e = blockIdx.y;
    __shared__ unsigned long long smax[KM];
    __shared__ int lastFlag;
    if (threadIdx.x < KM) smax[threadIdx.x] = 0ull;
    __syncthreads();
    const int i = blockIdx.x * BLK + threadIdx.x;
    if (i < N) {
        int t = tidx[(size_t)e * N + i];
        if (t > 0) {
            float bc = clipb(beta[(size_t)e * N + i]);
            unsigned long long pack =
                ((unsigned long long)__float_as_uint(bc) << 32) |
                (unsigned long long)(unsigned)(N - 1 - i);
            atomicMax(&smax[t], pack);
        }
    }
    __syncthreads();
    if (threadIdx.x < KM) {
        unsigned long long v = smax[threadIdx.x];
        if (v) atomicMax(&packs[e * KM + threadIdx.x], v);
    }

    if (threadIdx.x == 0) {
        __threadfence();
        unsigned int old = atomicAdd(&cnt[0], 1u);
        lastFlag = (old == gridDim.x * gridDim.y - 1u);
    }
    __syncthreads();
    if (!lastFlag) return;

    // last block: build packed alpha table (atomic reads = coherent cross-XCD)
    for (int s = threadIdx.x; s < B * KM; s += BLK) {
        unsigned long long v = atomicMax(&packs[s], 0ull);
        int e2 = s / KM, k = s - e2 * KM;
        float x = 0.f, y = 0.f, q = 0.f, bw = 0.f;
        if (v) {
            int idx = N - 1 - (int)(unsigned)(v & 0xffffffffull);
            bw = __uint_as_float((unsigned)(v >> 32));     // clipped beta_alpha
            float at = fast_atanh(bw);
            q = fmaf(at, at, QMIN);                        // q_alpha (0 => invalid)
            const float2 cp = ((const float2*)cc)[(size_t)e2 * N + idx];
            x = cp.x; y = cp.y;
        }
        int g = k >> 2, m = k & 3;
        float* basep = pkf + (size_t)(e2 * KG + g) * 12;
        basep[(m >> 1) * 4 + (m & 1) * 2 + 0] = x;
        basep[(m >> 1) * 4 + (m & 1) * 2 + 1] = y;
        basep[8 + m] = q;
        abw[s] = bw;
    }
}

// ---- K2: main pass (LDS-staged packed alpha) + last-block finalize ----
__global__ void __launch_bounds__(BLK)
k_main(const float* __restrict__ beta, const float* __restrict__ cc,
       const float* __restrict__ pe,   const float* __restrict__ te,
       const int* __restrict__ tidx,   const float4* __restrict__ pk4,
       const float* __restrict__ abw,
       float* __restrict__ enm, float* __restrict__ eden,
       float* __restrict__ scal, unsigned int* __restrict__ cnt,
       float* __restrict__ out, int N, int B) {
    const int e = blockIdx.y;
    __shared__ float4 sa4[KG * 3];
    __shared__ float  sn[KM], sd[KM];
    __shared__ float  sw[12];
    __shared__ int    lastFlag;
    if (threadIdx.x < KG * 3) sa4[threadIdx.x] = pk4[e * KG * 3 + threadIdx.x];
    if (threadIdx.x < KM) { sn[threadIdx.x] = 0.f; sd[threadIdx.x] = 0.f; }
    __syncthreads();

    const size_t base = (size_t)e * N;
    const int i = blockIdx.x * BLK + threadIdx.x;
    const bool ok = i < N;
    const size_t ii = base + (ok ? i : 0);
    const float2 cp = ((const float2*)cc)[ii];
    const float  bc = clipb(beta[ii]);
    const int    t  = ok ? tidx[ii] : 0;
    const float  at = fast_atanh(bc);
    const float  qq = ok ? fmaf(at, at, QMIN) : 0.f;   // qq=0 kills pad-hit lv

    float r0 = 0.f, r1 = 0.f, r2 = 0.f, r3 = 0.f;
    #pragma unroll 8
    for (int g = 0; g < KG; ++g) {
        float4 xy01 = sa4[g * 3 + 0];
        float4 xy23 = sa4[g * 3 + 1];
        float4 q4   = sa4[g * 3 + 2];
        float dx0 = cp.x - xy01.x, dy0 = cp.y - xy01.y;
        float dx1 = cp.x - xy01.z, dy1 = cp.y - xy01.w;
        float dx2 = cp.x - xy23.x, dy2 = cp.y - xy23.y;
        float dx3 = cp.x - xy23.z, dy3 = cp.y - xy23.w;
        float d0 = fmaf(dx0, dx0, fmaf(dy0, dy0, EPSF));
        float d1 = fmaf(dx1, dx1, fmaf(dy1, dy1, EPSF));
        float d2 = fmaf(dx2, dx2, fmaf(dy2, dy2, EPSF));
        float d3 = fmaf(dx3, dx3, fmaf(dy3, dy3, EPSF));
        r0 = fmaf(fmaxf(1.f - __builtin_amdgcn_sqrtf(d0), 0.f), q4.x, r0);
        r1 = fmaf(fmaxf(1.f - __builtin_amdgcn_sqrtf(d1), 0.f), q4.y, r1);
        r2 = fmaf(fmaxf(1.f - __builtin_amdgcn_sqrtf(d2), 0.f), q4.z, r2);
        r3 = fmaf(fmaxf(1.f - __builtin_amdgcn_sqrtf(d3), 0.f), q4.w, r3);
    }
    float rep = (r0 + r1) + (r2 + r3);
    float att = 0.f, bn = 0.f, cn = 0.f;

    if (t > 0) {                        // t>0 implies ok (pad hits use t=0)
        const float* sf = (const float*)sa4;
        int g = t >> 2, m = t & 3;
        float xo = sf[g * 12 + (m >> 1) * 4 + (m & 1) * 2 + 0];
        float yo = sf[g * 12 + (m >> 1) * 4 + (m & 1) * 2 + 1];
        float qo = sf[g * 12 + 8 + m];
        float dx = cp.x - xo, dy = cp.y - yo;
        float d2 = fmaf(dx, dx, dy * dy);
        att = d2 * qo;                                   // attractive (no eps)
        rep -= fmaxf(1.f - __builtin_amdgcn_sqrtf(d2 + EPSF), 0.f) * qo;
        float tev = te[ii];
        float edv = (pe[ii] - tev) * __builtin_amdgcn_rcpf(tev + 1.f);
        float ad  = fabsf(edv);
        float eh  = (ad <= 2.f) ? 0.5f * ad * ad : 2.f * (ad - 1.f);
        atomicAdd(&sn[t], bc * eh);
        atomicAdd(&sd[t], bc);
    } else if (ok) { bn = bc; cn = 1.f; }
    float lv = qq * (att + rep);
    __syncthreads();

    if (threadIdx.x < KM) {
        float vd = sd[threadIdx.x];
        if (vd != 0.f) {
            atomicAdd(&enm [e * KM + threadIdx.x], sn[threadIdx.x]);
            atomicAdd(&eden[e * KM + threadIdx.x], vd);
        }
    }
    for (int off = 32; off > 0; off >>= 1) {
        lv += __shfl_down(lv, off);
        bn += __shfl_down(bn, off);
        cn += __shfl_down(cn, off);
    }
    const int wid = threadIdx.x >> 6;
    if ((threadIdx.x & 63) == 0) { sw[wid] = lv; sw[4 + wid] = bn; sw[8 + wid] = cn; }
    __syncthreads();
    if (threadIdx.x == 0) {
        atomicAdd(&scal[e * 8 + 0], (sw[0] + sw[1]) + (sw[2] + sw[3]));
        atomicAdd(&scal[e * 8 + 3], (sw[4] + sw[5]) + (sw[6] + sw[7]));
        atomicAdd(&scal[e * 8 + 4], (sw[8] + sw[9]) + (sw[10] + sw[11]));
    }

    // ---- last-block-done finalize ----
    if (threadIdx.x == 0) {
        __threadfence();
        unsigned int old = atomicAdd(&cnt[1], 1u);
        lastFlag = (old == gridDim.x * gridDim.y - 1u);
    }
    __syncthreads();
    if (!lastFlag) return;
    __threadfence();

    volatile float* ven = enm;
    volatile float* ved = eden;
    volatile float* vsc = scal;
    float tot = 0.f;
    for (int ev = 0; ev < B; ++ev) {
        float lb = 0.f, nv = 0.f, le = 0.f;
        if (threadIdx.x < KM) {
            float bw = abw[ev * KM + threadIdx.x];
            if (bw > 0.f) {
                lb = 1.f - bw;
                nv = 1.f;
                le = ven[ev * KM + threadIdx.x] / (ved[ev * KM + threadIdx.x] + EPSF);
            }
        }
        for (int off = 32; off > 0; off >>= 1) {
            lb += __shfl_down(lb, off);
            nv += __shfl_down(nv, off);
            le += __shfl_down(le, off);
        }
        if ((threadIdx.x & 63) == 0) { sw[wid] = lb; sw[4 + wid] = nv; sw[8 + wid] = le; }
        __syncthreads();
        if (threadIdx.x == 0) {
            float lbs = (sw[0] + sw[1]) + (sw[2] + sw[3]);
            float nvs = (sw[4] + sw[5]) + (sw[6] + sw[7]);
            float les = (sw[8] + sw[9]) + (sw[10] + sw[11]);
            float nobj = nvs + EPSF;
            tot += vsc[ev * 8 + 0] / (float)N + lbs / nobj
                 + vsc[ev * 8 + 3] / (vsc[ev * 8 + 4] + EPSF) + les / nobj;
        }
        __syncthreads();
    }
    if (threadIdx.x == 0) out[0] = tot / (float)B;
}

extern "C" void kernel_launch(void* const* d_in, const int* in_sizes, int n_in,
                              void* d_out, int out_size, void* d_ws, size_t ws_size,
                              hipStream_t stream) {
    const int B = 4;
    const int N = in_sizes[0] / B;               // beta is [B,N,1]
    const int MB = (N + BLK - 1) / BLK;          // 256-hit tiles

    const float* beta = (const float*)d_in[0];
    const float* cc   = (const float*)d_in[1];
    const float* pe   = (const float*)d_in[2];
    const float* te   = (const float*)d_in[3];
    const int*   tidx = (const int*)  d_in[4];
    float* out = (float*)d_out;

    // ws: packs u64[B*KM] | pk4 float4[B*KG*3] | abw f32[B*KM]
    //     | enm f32[B*KM] | eden f32[B*KM] | scal f32[B*8] | cnt u32[4]
    char* ws = (char*)d_ws;
    unsigned long long* packs = (unsigned long long*)ws;
    float4* pk4 = (float4*)(ws + (size_t)B * KM * 8);
    float*  pkf = (float*)pk4;
    float*  abw = (float*)(pk4 + B * KG * 3);
    float*  enm = abw + B * KM;
    float*  eden = enm + B * KM;
    float*  scal = eden + B * KM;
    unsigned int* cnt = (unsigned int*)(scal + B * 8);
    const size_t zeroBytes = (char*)(cnt + 4) - ws;

    (void)hipMemsetAsync(d_ws, 0, zeroBytes, stream);
    k_amax<<<dim3(MB, B), dim3(BLK), 0, stream>>>(beta, tidx, cc, packs, pkf, abw, cnt, N, B);
    k_main<<<dim3(MB, B), dim3(BLK), 0, stream>>>(
        beta, cc, pe, te, tidx, pk4, abw, enm, eden, scal, cnt, out, N, B);
}

// Round 9
// 99.986 us; speedup vs baseline: 1.2150x; 1.2150x over previous
//
#include <hip/hip_runtime.h>
#include <math.h>

#define KM 192
#define EPSF 1e-6f
#define QMIN 0.5f
#define BLKA 256
#define HA 4
#define TILEA (BLKA * HA)    // 1024 hits per argmax tile
#define BLKM 256
#define TILEM (BLKM * 2)     // 512 hits per main tile (H=2)

__device__ __forceinline__ float clipb(float b) {
    return fminf(fmaxf(b, 1e-4f), 1.0f - 1e-4f);
}
// atanh(b) = 0.5*ln((1+b)/(1-b)); b in [1e-4, 1-1e-4]
__device__ __forceinline__ float fast_atanh(float b) {
    float r = (1.f + b) * __builtin_amdgcn_rcpf(1.f - b);
    return 0.34657359f * __builtin_amdgcn_logf(r);
}

// ---- K1: per-tile argmax partials into scratch (no global atomics) ----
// pack = (bits(clip(beta)) << 32) | (N-1-i): beta>0 -> bits monotone; low word
// reproduces jnp.argmax first-index tiebreak. argmax(beta) == argmax(q).
__global__ void __launch_bounds__(BLKA)
k_amax(const float* __restrict__ beta, const int* __restrict__ tidx,
       unsigned long long* __restrict__ pscr, int N, int HBT) {
    const int e = blockIdx.y;
    __shared__ unsigned long long smax[KM];
    for (int k = threadIdx.x; k < KM; k += BLKA) smax[k] = 0ull;
    __syncthreads();
    const size_t base = (size_t)e * N;
    #pragma unroll
    for (int h = 0; h < HA; ++h) {
        int i = blockIdx.x * TILEA + h * BLKA + threadIdx.x;
        if (i < N) {
            int t = tidx[base + i];
            if (t > 0) {
                float bc = clipb(beta[base + i]);
                unsigned long long pack =
                    ((unsigned long long)__float_as_uint(bc) << 32) |
                    (unsigned long long)(unsigned)(N - 1 - i);
                atomicMax(&smax[t], pack);
            }
        }
    }
    __syncthreads();
    unsigned long long* row = pscr + ((size_t)e * HBT + blockIdx.x) * KM;
    for (int k = threadIdx.x; k < KM; k += BLKA) row[k] = smax[k];
}

// ---- K2: build alpha table (x, y, q_a*valid, beta_a stored separately);
//          zero enm/eden/scal. 4 blocks (one per event). ----
__global__ void __launch_bounds__(256)
k_alpha(const unsigned long long* __restrict__ pscr, const float* __restrict__ cc,
        float4* __restrict__ alpha, float* __restrict__ abw,
        float* __restrict__ enm, float* __restrict__ eden,
        float* __restrict__ scal, int N, int HBT) {
    const int e = blockIdx.x;
    const int k = threadIdx.x;
    if (k < KM) {
        const unsigned long long* pk = pscr + (size_t)e * HBT * KM + k;
        unsigned long long v = 0ull;
        #pragma unroll 8
        for (int t = 0; t < HBT; ++t) {
            unsigned long long p = pk[(size_t)t * KM];
            if (p > v) v = p;
        }
        float4 a = make_float4(0.f, 0.f, 0.f, 0.f);
        float bw = 0.f;
        if (v) {
            int idx = N - 1 - (int)(unsigned)(v & 0xffffffffull);
            bw = __uint_as_float((unsigned)(v >> 32));     // clipped beta_alpha
            float at = fast_atanh(bw);
            float2 cp = ((const float2*)cc)[(size_t)e * N + idx];
            a.x = cp.x; a.y = cp.y;
            a.z = fmaf(at, at, QMIN);                      // q_alpha (0 => invalid)
        }
        alpha[e * KM + k] = a;
        abw  [e * KM + k] = bw;
    }
    for (int z = threadIdx.x; z < KM; z += 256) {
        enm [e * KM + z] = 0.f;
        eden[e * KM + z] = 0.f;
    }
    if (threadIdx.x < 8) scal[e * 8 + threadIdx.x] = 0.f;
}

// ---- K3: main pass, H=2 hits/thread, uniform global float4 alpha loads ----
__global__ void __launch_bounds__(BLKM, 4)
k_main(const float* __restrict__ beta, const float* __restrict__ cc,
       const float* __restrict__ pe,   const float* __restrict__ te,
       const int* __restrict__ tidx,   const float4* __restrict__ alpha,
       float* __restrict__ enm, float* __restrict__ eden,
       float* __restrict__ scal, int N) {
    const int e = blockIdx.y;
    __shared__ float sn[KM], sd[KM];
    __shared__ float sw[12];
    for (int k = threadIdx.x; k < KM; k += BLKM) { sn[k] = 0.f; sd[k] = 0.f; }
    __syncthreads();

    const size_t base = (size_t)e * N;
    const int ia = blockIdx.x * TILEM + threadIdx.x;
    const int ib = ia + BLKM;
    const bool oka = ia < N, okb = ib < N;
    const size_t iia = base + (oka ? ia : 0);
    const size_t iib = base + (okb ? ib : 0);
    const float2 ca = ((const float2*)cc)[iia];
    const float2 cb = ((const float2*)cc)[iib];
    const float bca = clipb(beta[iia]);
    const float bcb = clipb(beta[iib]);
    const int   ta  = oka ? tidx[iia] : 0;
    const int   tb  = okb ? tidx[iib] : 0;
    const float ha_ = fast_atanh(bca);
    const float hb_ = fast_atanh(bcb);
    const float qa  = oka ? fmaf(ha_, ha_, QMIN) : 0.f;   // 0 kills pad-hit lv
    const float qb  = okb ? fmaf(hb_, hb_, QMIN) : 0.f;

    const float4* __restrict__ ae = alpha + e * KM;       // uniform (scalar) loads
    float ra0 = 0.f, ra1 = 0.f, rb0 = 0.f, rb1 = 0.f;
    #pragma unroll 8
    for (int k = 0; k < KM; k += 2) {
        float4 a0 = ae[k], a1 = ae[k + 1];
        float dxa0 = ca.x - a0.x, dya0 = ca.y - a0.y;
        float dxa1 = ca.x - a1.x, dya1 = ca.y - a1.y;
        float dxb0 = cb.x - a0.x, dyb0 = cb.y - a0.y;
        float dxb1 = cb.x - a1.x, dyb1 = cb.y - a1.y;
        float da0 = fmaf(dxa0, dxa0, fmaf(dya0, dya0, EPSF));
        float da1 = fmaf(dxa1, dxa1, fmaf(dya1, dya1, EPSF));
        float db0 = fmaf(dxb0, dxb0, fmaf(dyb0, dyb0, EPSF));
        float db1 = fmaf(dxb1, dxb1, fmaf(dyb1, dyb1, EPSF));
        ra0 = fmaf(fmaxf(1.f - __builtin_amdgcn_sqrtf(da0), 0.f), a0.z, ra0);
        ra1 = fmaf(fmaxf(1.f - __builtin_amdgcn_sqrtf(da1), 0.f), a1.z, ra1);
        rb0 = fmaf(fmaxf(1.f - __builtin_amdgcn_sqrtf(db0), 0.f), a0.z, rb0);
        rb1 = fmaf(fmaxf(1.f - __builtin_amdgcn_sqrtf(db1), 0.f), a1.z, rb1);
    }
    float repa = ra0 + ra1, repb = rb0 + rb1;
    float atta = 0.f, attb = 0.f, bn = 0.f, cn = 0.f;

    if (ta > 0) {                       // t>0 implies ok (pad hits use t=0)
        float4 av = ae[ta];             // divergent, L1-resident (3KB table)
        float dx = ca.x - av.x, dy = ca.y - av.y;
        float d2 = fmaf(dx, dx, dy * dy);
        atta = d2 * av.z;
        repa -= fmaxf(1.f - __builtin_amdgcn_sqrtf(d2 + EPSF), 0.f) * av.z;
        float tev = te[iia];
        float edv = (pe[iia] - tev) * __builtin_amdgcn_rcpf(tev + 1.f);
        float ad  = fabsf(edv);
        float eh  = (ad <= 2.f) ? 0.5f * ad * ad : 2.f * (ad - 1.f);
        atomicAdd(&sn[ta], bca * eh);
        atomicAdd(&sd[ta], bca);
    } else if (oka) { bn += bca; cn += 1.f; }

    if (tb > 0) {
        float4 av = ae[tb];
        float dx = cb.x - av.x, dy = cb.y - av.y;
        float d2 = fmaf(dx, dx, dy * dy);
        attb = d2 * av.z;
        repb -= fmaxf(1.f - __builtin_amdgcn_sqrtf(d2 + EPSF), 0.f) * av.z;
        float tev = te[iib];
        float edv = (pe[iib] - tev) * __builtin_amdgcn_rcpf(tev + 1.f);
        float ad  = fabsf(edv);
        float eh  = (ad <= 2.f) ? 0.5f * ad * ad : 2.f * (ad - 1.f);
        atomicAdd(&sn[tb], bcb * eh);
        atomicAdd(&sd[tb], bcb);
    } else if (okb) { bn += bcb; cn += 1.f; }

    float lv = fmaf(qa, atta + repa, qb * (attb + repb));
    __syncthreads();

    if (threadIdx.x < KM) {
        float vd = sd[threadIdx.x];
        if (vd != 0.f) {
            atomicAdd(&enm [e * KM + threadIdx.x], sn[threadIdx.x]);
            atomicAdd(&eden[e * KM + threadIdx.x], vd);
        }
    }
    for (int off = 32; off > 0; off >>= 1) {
        lv += __shfl_down(lv, off);
        bn += __shfl_down(bn, off);
        cn += __shfl_down(cn, off);
    }
    const int wid = threadIdx.x >> 6;
    if ((threadIdx.x & 63) == 0) { sw[wid] = lv; sw[4 + wid] = bn; sw[8 + wid] = cn; }
    __syncthreads();
    if (threadIdx.x == 0) {
        atomicAdd(&scal[e * 8 + 0], (sw[0] + sw[1]) + (sw[2] + sw[3]));
        atomicAdd(&scal[e * 8 + 3], (sw[4] + sw[5]) + (sw[6] + sw[7]));
        atomicAdd(&scal[e * 8 + 4], (sw[8] + sw[9]) + (sw[10] + sw[11]));
    }
}

// ---- K4: finalize (1 block) ----
__global__ void __launch_bounds__(256)
k_fin(const float* __restrict__ enm, const float* __restrict__ eden,
      const float* __restrict__ abw, const float* __restrict__ scal,
      float* __restrict__ out, int N, int B) {
    __shared__ float sred[12];
    const int wid = threadIdx.x >> 6;
    float tot = 0.f;
    for (int ev = 0; ev < B; ++ev) {
        float lb = 0.f, nv = 0.f, le = 0.f;
        if (threadIdx.x < KM) {
            float bw = abw[ev * KM + threadIdx.x];
            if (bw > 0.f) {
                lb = 1.f - bw;
                nv = 1.f;
                le = enm[ev * KM + threadIdx.x] / (eden[ev * KM + threadIdx.x] + EPSF);
            }
        }
        for (int off = 32; off > 0; off >>= 1) {
            lb += __shfl_down(lb, off);
            nv += __shfl_down(nv, off);
            le += __shfl_down(le, off);
        }
        if ((threadIdx.x & 63) == 0) { sred[wid] = lb; sred[4 + wid] = nv; sred[8 + wid] = le; }
        __syncthreads();
        if (threadIdx.x == 0) {
            float lbs = (sred[0] + sred[1]) + (sred[2] + sred[3]);
            float nvs = (sred[4] + sred[5]) + (sred[6] + sred[7]);
            float les = (sred[8] + sred[9]) + (sred[10] + sred[11]);
            float nobj = nvs + EPSF;
            tot += scal[ev * 8 + 0] / (float)N + lbs / nobj
                 + scal[ev * 8 + 3] / (scal[ev * 8 + 4] + EPSF) + les / nobj;
        }
        __syncthreads();
    }
    if (threadIdx.x == 0) out[0] = tot / (float)B;
}

extern "C" void kernel_launch(void* const* d_in, const int* in_sizes, int n_in,
                              void* d_out, int out_size, void* d_ws, size_t ws_size,
                              hipStream_t stream) {
    const int B = 4;
    const int N = in_sizes[0] / B;               // beta is [B,N,1]
    const int HBT = (N + TILEA - 1) / TILEA;     // argmax tiles of 1024
    const int MB  = (N + TILEM - 1) / TILEM;     // main tiles of 512

    const float* beta = (const float*)d_in[0];
    const float* cc   = (const float*)d_in[1];
    const float* pe   = (const float*)d_in[2];
    const float* te   = (const float*)d_in[3];
    const int*   tidx = (const int*)  d_in[4];
    float* out = (float*)d_out;

    // ws: pscr u64[B*HBT*KM] | alpha float4[B*KM] | abw f32[B*KM]
    //     | enm f32[B*KM] | eden f32[B*KM] | scal f32[B*8]
    char* ws = (char*)d_ws;
    unsigned long long* pscr = (unsigned long long*)ws;
    float4* alpha = (float4*)(ws + (size_t)B * HBT * KM * 8);
    float*  abw   = (float*)(alpha + B * KM);
    float*  enm   = abw  + B * KM;
    float*  eden  = enm  + B * KM;
    float*  scal  = eden + B * KM;

    k_amax<<<dim3(HBT, B), dim3(BLKA), 0, stream>>>(beta, tidx, pscr, N, HBT);
    k_alpha<<<dim3(B), dim3(256), 0, stream>>>(pscr, cc, alpha, abw, enm, eden, scal, N, HBT);
    k_main<<<dim3(MB, B), dim3(BLKM), 0, stream>>>(
        beta, cc, pe, te, tidx, alpha, enm, eden, scal, N);
    k_fin<<<dim3(1), dim3(256), 0, stream>>>(enm, eden, abw, scal, out, N, B);
}